// Round 1
// baseline (104.406 us; speedup 1.0000x reference)
//
#include <hip/hip_runtime.h>
#include <hip/hip_bf16.h>

#define NPIX 65536
#define NRAYS 65536
#define SS 48
#define NC 256
#define ND 16

#define NBLK_A 128
#define NBLK_C 128

// workspace layout (floats)
#define WS_CNTPART 0
#define WS_USUMPART (NBLK_A*NC)                    // 32768
#define WS_DEVPART  (WS_USUMPART + NBLK_A*NC*ND)   // 557056
#define WS_CNT      (WS_DEVPART + NBLK_C*NC)       // 589824
#define WS_U        (WS_CNT + NC)                  // 590080
#define WS_UPHI     (WS_U + NC*ND)                 // 594176
#define WS_BIAS     (WS_UPHI + NC*ND)              // 598272
#define WS_SCAL     (WS_BIAS + NC)                 // 598528  [0]=norm [1]=wsum [2]=proto [3]=pad

// Pass 1 over pixels: rgb loss, opacity loss, per-block class counts + semantic sums,
// norm-loss partials.
__global__ __launch_bounds__(256) void kA(
    const float* __restrict__ rgb_pred, const float* __restrict__ rgb_gt,
    const float* __restrict__ opacity, const int* __restrict__ sam,
    const float* __restrict__ semantic,
    float* __restrict__ o_rgb, float* __restrict__ o_opac,
    float* __restrict__ cntpart, float* __restrict__ usumpart,
    float* __restrict__ scal)
{
    __shared__ float cnt_s[NC];
    __shared__ float us_s[NC*ND];
    __shared__ float red_s[8];
    const int t = threadIdx.x;
    const int b = blockIdx.x;
    for (int j = t; j < NC; j += 256) cnt_s[j] = 0.f;
    for (int j = t; j < NC*ND; j += 256) us_s[j] = 0.f;
    __syncthreads();
    float nloc = 0.f, wloc = 0.f;
#pragma unroll
    for (int p = 0; p < 2; ++p) {
        const int i = (b*2 + p)*256 + t;
        // rgb loss
        const float pr0 = rgb_pred[3*i+0], pr1 = rgb_pred[3*i+1], pr2 = rgb_pred[3*i+2];
        const float g0 = rgb_gt[3*i+0],  g1 = rgb_gt[3*i+1],  g2 = rgb_gt[3*i+2];
        const float d0 = pr0-g0, d1 = pr1-g1, d2 = pr2-g2;
        o_rgb[3*i+0] = d0*d0; o_rgb[3*i+1] = d1*d1; o_rgb[3*i+2] = d2*d2;
        // opacity loss
        const float o = opacity[i] + 1e-10f;
        o_opac[i] = -0.001f * o * logf(o);
        // semantic accumulation
        const float4* sp = (const float4*)(semantic + (size_t)i*ND);
        const float4 a0 = sp[0], a1 = sp[1], a2 = sp[2], a3 = sp[3];
        const int seg = sam[i];
        if (seg > 0) {
            const int cl = seg - 1;
            const float ss =
                a0.x*a0.x + a0.y*a0.y + a0.z*a0.z + a0.w*a0.w +
                a1.x*a1.x + a1.y*a1.y + a1.z*a1.z + a1.w*a1.w +
                a2.x*a2.x + a2.y*a2.y + a2.z*a2.z + a2.w*a2.w +
                a3.x*a3.x + a3.y*a3.y + a3.z*a3.z + a3.w*a3.w;
            const float dn = sqrtf(ss) - 1.f;
            nloc += dn*dn;
            wloc += 1.f;
            atomicAdd(&cnt_s[cl], 1.f);
            float* up = us_s + cl*ND;
            atomicAdd(up+0,  a0.x); atomicAdd(up+1,  a0.y);
            atomicAdd(up+2,  a0.z); atomicAdd(up+3,  a0.w);
            atomicAdd(up+4,  a1.x); atomicAdd(up+5,  a1.y);
            atomicAdd(up+6,  a1.z); atomicAdd(up+7,  a1.w);
            atomicAdd(up+8,  a2.x); atomicAdd(up+9,  a2.y);
            atomicAdd(up+10, a2.z); atomicAdd(up+11, a2.w);
            atomicAdd(up+12, a3.x); atomicAdd(up+13, a3.y);
            atomicAdd(up+14, a3.z); atomicAdd(up+15, a3.w);
        }
    }
    __syncthreads();
    for (int j = t; j < NC; j += 256) cntpart[b*NC + j] = cnt_s[j];
    for (int j = t; j < NC*ND; j += 256) usumpart[b*NC*ND + j] = us_s[j];
    for (int off = 32; off > 0; off >>= 1) {
        nloc += __shfl_down(nloc, off);
        wloc += __shfl_down(wloc, off);
    }
    if ((t & 63) == 0) { red_s[t>>6] = nloc; red_s[4 + (t>>6)] = wloc; }
    __syncthreads();
    if (t == 0) {
        atomicAdd(&scal[0], red_s[0]+red_s[1]+red_s[2]+red_s[3]);
        atomicAdd(&scal[1], red_s[4]+red_s[5]+red_s[6]+red_s[7]);
    }
}

// Distortion loss: one thread per ray, within-ray exclusive prefix scan.
__global__ __launch_bounds__(256) void kDist(
    const float* __restrict__ wsv, const float* __restrict__ deltas,
    const float* __restrict__ tsv, const int* __restrict__ rays_a,
    float* __restrict__ o_dist)
{
    const int r = blockIdx.x*256 + threadIdx.x;
    const int start = rays_a[3*r + 1];
    const int cnt   = rays_a[3*r + 2];
    float W = 0.f, WT = 0.f, acc = 0.f;
    if (cnt == SS && ((start & 3) == 0)) {
        const float4* wp = (const float4*)(wsv + start);
        const float4* dp = (const float4*)(deltas + start);
        const float4* tp = (const float4*)(tsv + start);
#pragma unroll
        for (int j = 0; j < SS/4; ++j) {
            const float4 w4 = wp[j], d4 = dp[j], t4 = tp[j];
            acc += 2.f*w4.x*(t4.x*W - WT) + w4.x*w4.x*d4.x*(1.f/3.f);
            W += w4.x; WT += w4.x*t4.x;
            acc += 2.f*w4.y*(t4.y*W - WT) + w4.y*w4.y*d4.y*(1.f/3.f);
            W += w4.y; WT += w4.y*t4.y;
            acc += 2.f*w4.z*(t4.z*W - WT) + w4.z*w4.z*d4.z*(1.f/3.f);
            W += w4.z; WT += w4.z*t4.z;
            acc += 2.f*w4.w*(t4.w*W - WT) + w4.w*w4.w*d4.w*(1.f/3.f);
            W += w4.w; WT += w4.w*t4.w;
        }
    } else {
        for (int j = 0; j < cnt; ++j) {
            const float w = wsv[start+j], tt = tsv[start+j], dd = deltas[start+j];
            acc += 2.f*w*(tt*W - WT) + w*w*dd*(1.f/3.f);
            W += w; WT += w*tt;
        }
    }
    o_dist[r] = 0.001f * acc;
}

// Reduce per-block partials -> counts and class means u.
__global__ __launch_bounds__(256) void kP1(
    const float* __restrict__ cntpart, const float* __restrict__ usumpart,
    float* __restrict__ cnt, float* __restrict__ u)
{
    const int id = blockIdx.x*256 + threadIdx.x;   // 0..4095 = (c,k)
    const int c = id >> 4;
    float cs = 0.f, us = 0.f;
    for (int b = 0; b < NBLK_A; ++b) {
        cs += cntpart[b*NC + c];
        us += usumpart[b*NC*ND + id];
    }
    const float csafe = fmaxf(cs, 1.f);
    u[id] = us / csafe;
    if ((id & 15) == 0) cnt[c] = cs;
}

// Deviation pass: sum ||sem_i - u[cl_i]|| per class (per-block partials).
__global__ __launch_bounds__(256) void kC(
    const float* __restrict__ semantic, const int* __restrict__ sam,
    const float* __restrict__ u, float* __restrict__ devpart)
{
    __shared__ float u_s[NC*ND];
    __shared__ float dev_s[NC];
    const int t = threadIdx.x, b = blockIdx.x;
    for (int j = t; j < NC*ND; j += 256) u_s[j] = u[j];
    for (int j = t; j < NC; j += 256) dev_s[j] = 0.f;
    __syncthreads();
#pragma unroll
    for (int p = 0; p < 2; ++p) {
        const int i = (b*2 + p)*256 + t;
        const int seg = sam[i];
        if (seg > 0) {
            const int cl = seg - 1;
            const float4* sp = (const float4*)(semantic + (size_t)i*ND);
            const float4 a0 = sp[0], a1 = sp[1], a2 = sp[2], a3 = sp[3];
            const float4* up = (const float4*)(u_s + cl*ND);
            const float4 u0 = up[0], u1 = up[1], u2 = up[2], u3 = up[3];
            float q, d2 = 0.f;
            q = a0.x-u0.x; d2 += q*q;  q = a0.y-u0.y; d2 += q*q;
            q = a0.z-u0.z; d2 += q*q;  q = a0.w-u0.w; d2 += q*q;
            q = a1.x-u1.x; d2 += q*q;  q = a1.y-u1.y; d2 += q*q;
            q = a1.z-u1.z; d2 += q*q;  q = a1.w-u1.w; d2 += q*q;
            q = a2.x-u2.x; d2 += q*q;  q = a2.y-u2.y; d2 += q*q;
            q = a2.z-u2.z; d2 += q*q;  q = a2.w-u2.w; d2 += q*q;
            q = a3.x-u3.x; d2 += q*q;  q = a3.y-u3.y; d2 += q*q;
            q = a3.z-u3.z; d2 += q*q;  q = a3.w-u3.w; d2 += q*q;
            atomicAdd(&dev_s[cl], sqrtf(d2));
        }
    }
    __syncthreads();
    for (int j = t; j < NC; j += 256) devpart[b*NC + j] = dev_s[j];
}

// Reduce dev partials -> phi; emit uphi = u/phi and validity bias.
__global__ __launch_bounds__(256) void kP2(
    const float* __restrict__ devpart, const float* __restrict__ cnt,
    const float* __restrict__ u, float* __restrict__ uphi,
    float* __restrict__ bias)
{
    const int c = threadIdx.x;  // one block of 256
    float dv = 0.f;
    for (int b = 0; b < NBLK_C; ++b) dv += devpart[b*NC + c];
    const float cs = cnt[c];
    const float csafe = fmaxf(cs, 1.f);
    const float phiraw = dv / (csafe * logf(cs + 10.f));
    const float phi = fminf(fmaxf(phiraw * 10.f, 0.1f), 1.f);
    const float inv = 1.f / phi;
    bias[c] = (cs > 2.0f) ? 0.f : -1e30f;
    for (int k = 0; k < ND; ++k) uphi[c*ND + k] = u[c*ND + k] * inv;
}

// NCE pass: logits = sem . (u/phi), masked softmax denominator, proto-NCE sum.
__global__ __launch_bounds__(256) void kD(
    const float* __restrict__ semantic, const int* __restrict__ sam,
    const float* __restrict__ uphi, const float* __restrict__ bias,
    float* __restrict__ scal)
{
    __shared__ float red_s[4];
    const int i = blockIdx.x*256 + threadIdx.x;
    const float4* sp = (const float4*)(semantic + (size_t)i*ND);
    const float4 a0 = sp[0], a1 = sp[1], a2 = sp[2], a3 = sp[3];
    const int seg = sam[i];
    const int cl = (seg > 0) ? (seg - 1) : 0;
    const float4* up = (const float4*)uphi;
    float denom = 0.f, lcl = 0.f;
#pragma unroll 4
    for (int c = 0; c < NC; ++c) {
        const float4 u0 = up[4*c+0], u1 = up[4*c+1], u2 = up[4*c+2], u3 = up[4*c+3];
        const float dotv =
            a0.x*u0.x + a0.y*u0.y + a0.z*u0.z + a0.w*u0.w +
            a1.x*u1.x + a1.y*u1.y + a1.z*u1.z + a1.w*u1.w +
            a2.x*u2.x + a2.y*u2.y + a2.z*u2.z + a2.w*u2.w +
            a3.x*u3.x + a3.y*u3.y + a3.z*u3.z + a3.w*u3.w;
        denom += __expf(dotv + bias[c]);
        if (c == cl) lcl = dotv;
    }
    const float bcl = bias[cl];
    float contrib = ((seg > 0) && (bcl == 0.f)) ? (__logf(denom + 1e-6f) - lcl) : 0.f;
    for (int off = 32; off > 0; off >>= 1) contrib += __shfl_down(contrib, off);
    const int t = threadIdx.x;
    if ((t & 63) == 0) red_s[t>>6] = contrib;
    __syncthreads();
    if (t == 0) atomicAdd(&scal[2], red_s[0]+red_s[1]+red_s[2]+red_s[3]);
}

// Finalize scalar output.
__global__ void kE(const float* __restrict__ scal, float* __restrict__ o_sem)
{
    o_sem[0] = 1e-4f * scal[2] + 100.f * scal[0] / fmaxf(scal[1], 1.f);
}

extern "C" void kernel_launch(void* const* d_in, const int* in_sizes, int n_in,
                              void* d_out, int out_size, void* d_ws, size_t ws_size,
                              hipStream_t stream)
{
    const float* rgb_pred = (const float*)d_in[0];
    const float* rgb_gt   = (const float*)d_in[1];
    const float* opacity  = (const float*)d_in[2];
    const float* wsv      = (const float*)d_in[3];
    const float* deltas   = (const float*)d_in[4];
    const float* tsv      = (const float*)d_in[5];
    const int*   rays_a   = (const int*)d_in[6];
    const int*   sam      = (const int*)d_in[7];
    const float* semantic = (const float*)d_in[8];

    float* out    = (float*)d_out;
    float* o_rgb  = out;                 // 196608
    float* o_opac = out + 196608;        // 65536
    float* o_dist = out + 262144;        // 65536
    float* o_sem  = out + 327680;        // 1
    float* wsf    = (float*)d_ws;

    hipMemsetAsync(wsf + WS_SCAL, 0, 4*sizeof(float), stream);

    kA<<<NBLK_A, 256, 0, stream>>>(rgb_pred, rgb_gt, opacity, sam, semantic,
                                   o_rgb, o_opac,
                                   wsf + WS_CNTPART, wsf + WS_USUMPART,
                                   wsf + WS_SCAL);
    kDist<<<NRAYS/256, 256, 0, stream>>>(wsv, deltas, tsv, rays_a, o_dist);
    kP1<<<(NC*ND)/256, 256, 0, stream>>>(wsf + WS_CNTPART, wsf + WS_USUMPART,
                                         wsf + WS_CNT, wsf + WS_U);
    kC<<<NBLK_C, 256, 0, stream>>>(semantic, sam, wsf + WS_U, wsf + WS_DEVPART);
    kP2<<<1, 256, 0, stream>>>(wsf + WS_DEVPART, wsf + WS_CNT, wsf + WS_U,
                               wsf + WS_UPHI, wsf + WS_BIAS);
    kD<<<NPIX/256, 256, 0, stream>>>(semantic, sam, wsf + WS_UPHI,
                                     wsf + WS_BIAS, wsf + WS_SCAL);
    kE<<<1, 1, 0, stream>>>(wsf + WS_SCAL, o_sem);
}